// Round 21
// baseline (93.915 us; speedup 1.0000x reference)
//
#include <hip/hip_runtime.h>

#define KP    96      // K=85 padded to 96 k-rows (6 waves x 16)
#define NF    16
#define NCOL  117     // 16 + 85 + 16 output columns
#define PBLK  (KP * NF)   // 1536 floats per partial block
#define NB1   1024    // k1 grid (4 blocks/CU)

typedef __attribute__((ext_vector_type(8))) short bf16x8;
typedef __attribute__((ext_vector_type(4))) float f32x4;

__device__ __forceinline__ float fast_exp2(float x) {
#if __has_builtin(__builtin_amdgcn_exp2f)
    return __builtin_amdgcn_exp2f(x);
#else
    float r;
    asm volatile("v_exp_f32 %0, %1" : "=v"(r) : "v"(x));
    return r;
#endif
}

__device__ __forceinline__ unsigned short f2bf(float f) {   // RNE f32->bf16
    unsigned int u = __float_as_uint(f);
    u += 0x7FFFu + ((u >> 16) & 1u);
    return (unsigned short)(u >> 16);
}

__device__ __forceinline__ unsigned int pk_bf16(float lo, float hi) {
    unsigned int r;
    asm("v_cvt_pk_bf16_f32 %0, %1, %2" : "=v"(r) : "v"(lo), "v"(hi));
    return r;
}

// ---------------------------------------------------------------------------
// Kernel 1 (MFMA, double-buffered staging): partial QF. (R20 binary +
// flag reset for the k2 producer/consumer handshake.)
// ---------------------------------------------------------------------------
__global__ __launch_bounds__(384) void k1_partial(
    const float* __restrict__ X, const float* __restrict__ F,
    const float* __restrict__ QX, const float* __restrict__ omegaD,
    int K, int ntile, float* __restrict__ partial,
    unsigned int* __restrict__ flag)
{
    __shared__ float xs[2][4 * 32];            // x0|x1|x2|xn2 per buffer
    __shared__ unsigned short fsb[2][32 * 18]; // F tiles bf16, stride-18

    const int tid  = threadIdx.x;
    if (blockIdx.x == 0 && tid == 0) flag[0] = 0u;   // visible to k2 (next dispatch)

    const int lane = tid & 63;
    const int wv   = __builtin_amdgcn_readfirstlane(tid >> 6);  // 0..5
    const int kbase = wv * 16;
    const int m = lane & 15;
    const int g = lane >> 4;

    const int k = kbase + m;
    float qs0 = 0.f, qs1 = 0.f, qs2 = 0.f, cc = -3.0e8f, ss = 0.f;
    if (k < K) {
        const float qx = QX[k * 3 + 0];
        const float qy = QX[k * 3 + 1];
        const float qz = QX[k * 3 + 2];
        const float w  = omegaD[k];
        ss  = 1.4426950408889634f / (w * w);     // log2(e)/w^2
        qs0 = 2.f * ss * qx; qs1 = 2.f * ss * qy; qs2 = 2.f * ss * qz;
        cc  = ss * (qx * qx + qy * qy + qz * qz);
    }

    f32x4 acc = {0.f, 0.f, 0.f, 0.f};

#define STAGE(BUF, TILE)                                                        \
    do {                                                                        \
        const int pbase_ = (TILE) * 32;                                         \
        for (int idx = tid; idx < 512; idx += 384) {                            \
            const int p_ = idx >> 4, n_ = idx & 15;                             \
            fsb[BUF][p_ * 18 + n_] = f2bf(F[(size_t)(pbase_ + p_) * NF + n_]);  \
        }                                                                       \
        if (tid < 32) {                                                         \
            const float x0_ = X[(pbase_ + tid) * 3 + 0];                        \
            const float x1_ = X[(pbase_ + tid) * 3 + 1];                        \
            const float x2_ = X[(pbase_ + tid) * 3 + 2];                        \
            xs[BUF][tid]      = x0_;                                            \
            xs[BUF][32 + tid] = x1_;                                            \
            xs[BUF][64 + tid] = x2_;                                            \
            xs[BUF][96 + tid] = x0_ * x0_ + x1_ * x1_ + x2_ * x2_;              \
        }                                                                       \
    } while (0)

    int t = blockIdx.x;
    int cur = 0;
    if (t < ntile) STAGE(0, t);
    __syncthreads();

    while (t < ntile) {
        const int tn = t + gridDim.x;
        float e[8];
        unsigned short bs[8];
#pragma unroll
        for (int i = 0; i < 8; ++i) {
            const int p = g * 8 + i;
            const float x0 = xs[cur][p], x1 = xs[cur][32 + p];
            const float x2 = xs[cur][64 + p], xn2 = xs[cur][96 + p];
            float h = fmaf(xn2, ss, cc);
            h = fmaf(-x0, qs0, h);
            h = fmaf(-x1, qs1, h);
            h = fmaf(-x2, qs2, h);
            e[i] = fast_exp2(h);
            bs[i] = fsb[cur][p * 18 + m];
        }
        if (tn < ntile) STAGE(cur ^ 1, tn);

        union { bf16x8 v; unsigned int u[4]; } af, bf;
#pragma unroll
        for (int j = 0; j < 4; ++j) {
            af.u[j] = pk_bf16(e[2 * j], e[2 * j + 1]);
            bf.u[j] = (unsigned int)bs[2 * j] | ((unsigned int)bs[2 * j + 1] << 16);
        }
        acc = __builtin_amdgcn_mfma_f32_16x16x32_bf16(af.v, bf.v, acc, 0, 0, 0);

        __syncthreads();
        cur ^= 1;
        t = tn;
    }
#undef STAGE

    float* pb = partial + (size_t)blockIdx.x * PBLK;
#pragma unroll
    for (int r = 0; r < 4; ++r) {
        const int krow = kbase + g * 4 + r;
        pb[krow * NF + m] = acc[r];
    }
}

// ---------------------------------------------------------------------------
// Kernel 2 (fused reduce + output): blocks 0..95 reduce one k-row each ->
// QF + threadfence + atomic flag (R15-proven visibility pattern, but
// PARALLEL across 96 CUs); all 1024 blocks poll-sleep on the flag
// (bounded: timeout falls back to a local redundant reduction with the
// IDENTICAL summation order -> bitwise-same QF, no deadlock possible).
// Then the R20 k2 body: in-block B2, 32-row double-buffered stages.
// ---------------------------------------------------------------------------
__global__ __launch_bounds__(256, 4) void k2_out(
    const float* __restrict__ F, const float* __restrict__ partial,
    const float* __restrict__ omegaF, int nb,
    float* __restrict__ QF, unsigned int* __restrict__ flag,
    float* __restrict__ out)
{
    __shared__ __align__(16) float row[2][32 * NCOL];  // 29.25 KB
    __shared__ __align__(16) float qf[85 * 16];        // 5.3 KB
    __shared__ float b2[256];                          // 1 KB
    __shared__ float reds[16][17];                     // 1.06 KB
    __shared__ int ready;

    const int tid = threadIdx.x;
    const int q = tid & 31, pp = tid >> 5;

    // one k-row reduction: 16 gg-groups x 4 streams; LDS tree; fixed order.
#define ROW_REDUCE(KROW, DST)                                                   \
    do {                                                                        \
        const int f_ = tid & 15, gg_ = tid >> 4;                                \
        const float* base_ = partial + (KROW) * NF + f_;                        \
        float s0 = 0.f, s1 = 0.f, s2 = 0.f, s3 = 0.f;                           \
        int b_ = gg_;                                                           \
        for (; b_ + 48 < nb; b_ += 64) {                                        \
            s0 += base_[(size_t)(b_ +  0) * PBLK];                              \
            s1 += base_[(size_t)(b_ + 16) * PBLK];                              \
            s2 += base_[(size_t)(b_ + 32) * PBLK];                              \
            s3 += base_[(size_t)(b_ + 48) * PBLK];                              \
        }                                                                       \
        for (; b_ < nb; b_ += 16) s0 += base_[(size_t)b_ * PBLK];               \
        reds[gg_][f_] = (s0 + s1) + (s2 + s3);                                  \
        __syncthreads();                                                        \
        if (tid < 16) {                                                         \
            float t_ = 0.f;                                                     \
            _Pragma("unroll")                                                   \
            for (int g2_ = 0; g2_ < 16; ++g2_) t_ += reds[g2_][tid];            \
            DST;                                                                \
        }                                                                       \
        __syncthreads();                                                        \
    } while (0)

    // ---- producer phase: blocks 0..95 each reduce their k-row ----
    if (blockIdx.x < KP) {
        const int kk = blockIdx.x;
        ROW_REDUCE(kk, QF[kk * NF + tid] = t_ * omegaF[tid]);
        __threadfence();                    // device-scope release (R15-proven)
        if (tid == 0) atomicAdd(flag, 1u);
    }

    // ---- consumer wait (bounded; no deadlock possible) ----
    if (tid == 0) {
        int it = 0;
        while (atomicAdd(flag, 0u) < (unsigned int)KP) {
            __builtin_amdgcn_s_sleep(8);
            if (++it > 5000) break;         // ~1 ms cap
        }
        ready = (atomicAdd(flag, 0u) >= (unsigned int)KP) ? 1 : 0;
        __threadfence();
    }
    __syncthreads();

    if (ready) {
        for (int i = tid; i < 85 * 16; i += 256) qf[i] = QF[i];
    } else {
        // fallback: redundant local reduction, same order -> bitwise-same
        for (int kk = 0; kk < 85; ++kk)
            ROW_REDUCE(kk, qf[kk * 16 + tid] = t_ * omegaF[tid]);
    }
    __syncthreads();
#undef ROW_REDUCE

    // ---- B2 = QF^T QF in LDS ----
    {
        const int u = tid & 15, v = tid >> 4;
        float s = 0.f;
        for (int kk = 0; kk < 85; ++kk) s += qf[kk * 16 + v] * qf[kk * 16 + u];
        b2[tid] = s;
    }
    __syncthreads();

    float qr[3][NF];
#pragma unroll
    for (int j = 0; j < 3; ++j) {
        const int kk = q + 32 * j;
        if (kk < 85) {
#pragma unroll
            for (int u2 = 0; u2 < NF; ++u2) qr[j][u2] = qf[kk * 16 + u2];
        } else {
#pragma unroll
            for (int u2 = 0; u2 < NF; ++u2) qr[j][u2] = 0.f;
        }
    }
    float b2c[NF];
#pragma unroll
    for (int v = 0; v < NF; ++v) b2c[v] = b2[v * 16 + (q & 15)];

    const int chunk = blockIdx.x * 256;
#pragma unroll 2
    for (int st = 0; st < 8; ++st) {
        const int sbase = chunk + st * 32;
        float* bufp = row[st & 1];
        float fr[NF];
        {
            const float4* Fv = reinterpret_cast<const float4*>(F + (size_t)(sbase + pp) * NF);
            const float4 t0 = Fv[0], t1 = Fv[1], t2 = Fv[2], t3 = Fv[3];
            fr[0]=t0.x; fr[1]=t0.y; fr[2]=t0.z; fr[3]=t0.w;
            fr[4]=t1.x; fr[5]=t1.y; fr[6]=t1.z; fr[7]=t1.w;
            fr[8]=t2.x; fr[9]=t2.y; fr[10]=t2.z; fr[11]=t2.w;
            fr[12]=t3.x; fr[13]=t3.y; fr[14]=t3.z; fr[15]=t3.w;
        }
#pragma unroll
        for (int it = 0; it < 4; ++it) {
            float4 n0, n1, n2, n3;
            if (it < 3) {
                const float4* Fv = reinterpret_cast<const float4*>(
                    F + (size_t)(sbase + (it + 1) * 8 + pp) * NF);
                n0 = Fv[0]; n1 = Fv[1]; n2 = Fv[2]; n3 = Fv[3];
            }
            float* rp = &bufp[(it * 8 + pp) * NCOL];
#pragma unroll
            for (int j = 0; j < 3; ++j) {
                const int kk = q + 32 * j;
                float t = 0.f;
#pragma unroll
                for (int u2 = 0; u2 < NF; ++u2) t += fr[u2] * qr[j][u2];
                if (kk < 85) rp[16 + kk] = t;
            }
            if (q == 0) {
#pragma unroll
                for (int u2 = 0; u2 < NF; ++u2) rp[u2] = fr[u2];
            }
            if (q < 16) {
                float g = 0.f;
#pragma unroll
                for (int v = 0; v < NF; ++v) g += fr[v] * b2c[v];
                rp[101 + q] = g;
            }
            if (it < 3) {
                fr[0]=n0.x; fr[1]=n0.y; fr[2]=n0.z; fr[3]=n0.w;
                fr[4]=n1.x; fr[5]=n1.y; fr[6]=n1.z; fr[7]=n1.w;
                fr[8]=n2.x; fr[9]=n2.y; fr[10]=n2.z; fr[11]=n2.w;
                fr[12]=n3.x; fr[13]=n3.y; fr[14]=n3.z; fr[15]=n3.w;
            }
        }
        __syncthreads();
        {
            float4* dst = reinterpret_cast<float4*>(out + (size_t)sbase * NCOL);
            const float4* src = reinterpret_cast<const float4*>(bufp);
            for (int t2 = tid; t2 < (32 * NCOL) / 4; t2 += 256) dst[t2] = src[t2];
        }
    }
}

// ---------------------------------------------------------------------------
extern "C" void kernel_launch(void* const* d_in, const int* in_sizes, int n_in,
                              void* d_out, int out_size, void* d_ws, size_t ws_size,
                              hipStream_t stream)
{
    const float* X      = (const float*)d_in[0];
    const float* F      = (const float*)d_in[1];
    const float* QX     = (const float*)d_in[2];
    const float* omegaD = (const float*)d_in[3];
    const float* omegaF = (const float*)d_in[4];
    float* out = (float*)d_out;

    const int M = in_sizes[0] / 3;       // 262144
    const int K = in_sizes[3];           // 85
    const int ntile = M / 32;            // 8192

    int nb = (int)((ws_size / sizeof(float) - PBLK - 16) / PBLK);
    if (nb > NB1) nb = NB1;
    if (nb > ntile) nb = ntile;
    if (nb < 1) nb = 1;

    float* partial = (float*)d_ws;
    float* QFbuf   = partial + (size_t)nb * PBLK;
    unsigned int* flag = (unsigned int*)(QFbuf + PBLK);

    hipLaunchKernelGGL(k1_partial, dim3(nb), dim3(384), 0, stream,
                       X, F, QX, omegaD, K, ntile, partial, flag);
    hipLaunchKernelGGL(k2_out, dim3(M / 256), dim3(256), 0, stream,
                       F, partial, omegaF, nb, QFbuf, flag, out);
}

// Round 22
// 61.512 us; speedup vs baseline: 1.5268x; 1.5268x over previous
//
#include <hip/hip_runtime.h>

#define KP    96      // K=85 padded to 96 k-rows (6 waves x 16)
#define NF    16
#define NCOL  117     // 16 + 85 + 16 output columns
#define PBLK  (KP * NF)   // 1536 floats per partial block
#define NB1   1024    // k1 grid (4 blocks/CU)

typedef __attribute__((ext_vector_type(8))) short bf16x8;
typedef __attribute__((ext_vector_type(4))) float f32x4;

__device__ __forceinline__ float fast_exp2(float x) {
#if __has_builtin(__builtin_amdgcn_exp2f)
    return __builtin_amdgcn_exp2f(x);
#else
    float r;
    asm volatile("v_exp_f32 %0, %1" : "=v"(r) : "v"(x));
    return r;
#endif
}

__device__ __forceinline__ unsigned short f2bf(float f) {   // RNE f32->bf16
    unsigned int u = __float_as_uint(f);
    u += 0x7FFFu + ((u >> 16) & 1u);
    return (unsigned short)(u >> 16);
}

__device__ __forceinline__ unsigned int pk_bf16(float lo, float hi) {
    unsigned int r;
    asm("v_cvt_pk_bf16_f32 %0, %1, %2" : "=v"(r) : "v"(lo), "v"(hi));
    return r;
}

// ---------------------------------------------------------------------------
// Kernel 1 (MFMA, double-buffered staging): partial QF via
// v_mfma_f32_16x16x32_bf16. Stage tile t+1 into buf[t+1&1] while computing
// tile t -> ONE barrier per tile. F staged as bf16 stride-18 ushort rows
// (conflict-free); afrag packed with v_cvt_pk_bf16_f32.
// ---------------------------------------------------------------------------
__global__ __launch_bounds__(384) void k1_partial(
    const float* __restrict__ X, const float* __restrict__ F,
    const float* __restrict__ QX, const float* __restrict__ omegaD,
    int K, int ntile, float* __restrict__ partial)
{
    __shared__ float xs[2][4 * 32];            // x0|x1|x2|xn2 per buffer
    __shared__ unsigned short fsb[2][32 * 18]; // F tiles bf16, stride-18

    const int tid  = threadIdx.x;
    const int lane = tid & 63;
    const int wv   = __builtin_amdgcn_readfirstlane(tid >> 6);  // 0..5
    const int kbase = wv * 16;
    const int m = lane & 15;
    const int g = lane >> 4;

    const int k = kbase + m;
    float qs0 = 0.f, qs1 = 0.f, qs2 = 0.f, cc = -3.0e8f, ss = 0.f;
    if (k < K) {
        const float qx = QX[k * 3 + 0];
        const float qy = QX[k * 3 + 1];
        const float qz = QX[k * 3 + 2];
        const float w  = omegaD[k];
        ss  = 1.4426950408889634f / (w * w);     // log2(e)/w^2
        qs0 = 2.f * ss * qx; qs1 = 2.f * ss * qy; qs2 = 2.f * ss * qz;
        cc  = ss * (qx * qx + qy * qy + qz * qz);
    }

    f32x4 acc = {0.f, 0.f, 0.f, 0.f};

#define STAGE(BUF, TILE)                                                        \
    do {                                                                        \
        const int pbase_ = (TILE) * 32;                                         \
        for (int idx = tid; idx < 512; idx += 384) {                            \
            const int p_ = idx >> 4, n_ = idx & 15;                             \
            fsb[BUF][p_ * 18 + n_] = f2bf(F[(size_t)(pbase_ + p_) * NF + n_]);  \
        }                                                                       \
        if (tid < 32) {                                                         \
            const float x0_ = X[(pbase_ + tid) * 3 + 0];                        \
            const float x1_ = X[(pbase_ + tid) * 3 + 1];                        \
            const float x2_ = X[(pbase_ + tid) * 3 + 2];                        \
            xs[BUF][tid]      = x0_;                                            \
            xs[BUF][32 + tid] = x1_;                                            \
            xs[BUF][64 + tid] = x2_;                                            \
            xs[BUF][96 + tid] = x0_ * x0_ + x1_ * x1_ + x2_ * x2_;              \
        }                                                                       \
    } while (0)

    int t = blockIdx.x;
    int cur = 0;
    if (t < ntile) STAGE(0, t);
    __syncthreads();

    while (t < ntile) {
        const int tn = t + gridDim.x;
        float e[8];
        unsigned short bs[8];
#pragma unroll
        for (int i = 0; i < 8; ++i) {
            const int p = g * 8 + i;
            const float x0 = xs[cur][p], x1 = xs[cur][32 + p];
            const float x2 = xs[cur][64 + p], xn2 = xs[cur][96 + p];
            float h = fmaf(xn2, ss, cc);
            h = fmaf(-x0, qs0, h);
            h = fmaf(-x1, qs1, h);
            h = fmaf(-x2, qs2, h);
            e[i] = fast_exp2(h);
            bs[i] = fsb[cur][p * 18 + m];
        }
        if (tn < ntile) STAGE(cur ^ 1, tn);

        union { bf16x8 v; unsigned int u[4]; } af, bf;
#pragma unroll
        for (int j = 0; j < 4; ++j) {
            af.u[j] = pk_bf16(e[2 * j], e[2 * j + 1]);
            bf.u[j] = (unsigned int)bs[2 * j] | ((unsigned int)bs[2 * j + 1] << 16);
        }
        acc = __builtin_amdgcn_mfma_f32_16x16x32_bf16(af.v, bf.v, acc, 0, 0, 0);

        __syncthreads();
        cur ^= 1;
        t = tn;
    }
#undef STAGE

    float* pb = partial + (size_t)blockIdx.x * PBLK;
#pragma unroll
    for (int r = 0; r < 4; ++r) {
        const int krow = kbase + g * 4 + r;
        pb[krow * NF + m] = acc[r];
    }
}

// ---------------------------------------------------------------------------
// Kernel 1.5: fixed-order reduction of partials -> QF (applies omegaF).
// 512 threads/block: 32 loads/thread, 8 independent streams.
// ---------------------------------------------------------------------------
__global__ __launch_bounds__(512) void k1_reduce(
    const float* __restrict__ partial, const float* __restrict__ omegaF,
    int nb, float* __restrict__ QF)
{
    const int k = blockIdx.x, tid = threadIdx.x;
    const int f = tid & 15, g = tid >> 4;   // g: 0..31
    const float* base = partial + k * NF + f;
    float s0 = 0.f, s1 = 0.f, s2 = 0.f, s3 = 0.f;
    float s4 = 0.f, s5 = 0.f, s6 = 0.f, s7 = 0.f;
    int b = g;
    for (; b + 224 < nb; b += 256) {
        s0 += base[(size_t)(b +   0) * PBLK];
        s1 += base[(size_t)(b +  32) * PBLK];
        s2 += base[(size_t)(b +  64) * PBLK];
        s3 += base[(size_t)(b +  96) * PBLK];
        s4 += base[(size_t)(b + 128) * PBLK];
        s5 += base[(size_t)(b + 160) * PBLK];
        s6 += base[(size_t)(b + 192) * PBLK];
        s7 += base[(size_t)(b + 224) * PBLK];
    }
    for (; b < nb; b += 32) s0 += base[(size_t)b * PBLK];
    const float s = ((s0 + s1) + (s2 + s3)) + ((s4 + s5) + (s6 + s7));

    __shared__ float red[32][17];
    red[g][f] = s;
    __syncthreads();
    if (tid < 16) {
        float t = 0.f;
#pragma unroll
        for (int g2 = 0; g2 < 32; ++g2) t += red[g2][tid];
        QF[k * NF + tid] = t * omegaF[tid];
    }
}

// ---------------------------------------------------------------------------
// Kernel 2: double-buffered 32-row LDS stages + in-block B2 (at its
// ~22-25us traffic floor).
// ---------------------------------------------------------------------------
__global__ __launch_bounds__(256, 4) void k2_out(
    const float* __restrict__ F, const float* __restrict__ QFb,
    float* __restrict__ out)
{
    __shared__ __align__(16) float row[2][32 * NCOL];
    __shared__ __align__(16) float qf[85 * 16];
    __shared__ float b2[256];

    const int tid = threadIdx.x;
    const int q = tid & 31, pp = tid >> 5;

    for (int i = tid; i < 85 * 16; i += 256) qf[i] = QFb[i];
    __syncthreads();
    {
        const int u = tid & 15, v = tid >> 4;
        float s = 0.f;
        for (int k = 0; k < 85; ++k) s += qf[k * 16 + v] * qf[k * 16 + u];
        b2[tid] = s;
    }
    __syncthreads();

    float qr[3][NF];
#pragma unroll
    for (int j = 0; j < 3; ++j) {
        const int k = q + 32 * j;
        if (k < 85) {
#pragma unroll
            for (int u2 = 0; u2 < NF; ++u2) qr[j][u2] = qf[k * 16 + u2];
        } else {
#pragma unroll
            for (int u2 = 0; u2 < NF; ++u2) qr[j][u2] = 0.f;
        }
    }
    float b2c[NF];
#pragma unroll
    for (int v = 0; v < NF; ++v) b2c[v] = b2[v * 16 + (q & 15)];

    const int chunk = blockIdx.x * 256;
#pragma unroll 2
    for (int st = 0; st < 8; ++st) {
        const int sbase = chunk + st * 32;
        float* bufp = row[st & 1];
        float fr[NF];
        {
            const float4* Fv = reinterpret_cast<const float4*>(F + (size_t)(sbase + pp) * NF);
            const float4 t0 = Fv[0], t1 = Fv[1], t2 = Fv[2], t3 = Fv[3];
            fr[0]=t0.x; fr[1]=t0.y; fr[2]=t0.z; fr[3]=t0.w;
            fr[4]=t1.x; fr[5]=t1.y; fr[6]=t1.z; fr[7]=t1.w;
            fr[8]=t2.x; fr[9]=t2.y; fr[10]=t2.z; fr[11]=t2.w;
            fr[12]=t3.x; fr[13]=t3.y; fr[14]=t3.z; fr[15]=t3.w;
        }
#pragma unroll
        for (int it = 0; it < 4; ++it) {
            float4 n0, n1, n2, n3;
            if (it < 3) {
                const float4* Fv = reinterpret_cast<const float4*>(
                    F + (size_t)(sbase + (it + 1) * 8 + pp) * NF);
                n0 = Fv[0]; n1 = Fv[1]; n2 = Fv[2]; n3 = Fv[3];
            }
            float* rp = &bufp[(it * 8 + pp) * NCOL];
#pragma unroll
            for (int j = 0; j < 3; ++j) {
                const int k = q + 32 * j;
                float t = 0.f;
#pragma unroll
                for (int u2 = 0; u2 < NF; ++u2) t += fr[u2] * qr[j][u2];
                if (k < 85) rp[16 + k] = t;
            }
            if (q == 0) {
#pragma unroll
                for (int u2 = 0; u2 < NF; ++u2) rp[u2] = fr[u2];
            }
            if (q < 16) {
                float g = 0.f;
#pragma unroll
                for (int v = 0; v < NF; ++v) g += fr[v] * b2c[v];
                rp[101 + q] = g;
            }
            if (it < 3) {
                fr[0]=n0.x; fr[1]=n0.y; fr[2]=n0.z; fr[3]=n0.w;
                fr[4]=n1.x; fr[5]=n1.y; fr[6]=n1.z; fr[7]=n1.w;
                fr[8]=n2.x; fr[9]=n2.y; fr[10]=n2.z; fr[11]=n2.w;
                fr[12]=n3.x; fr[13]=n3.y; fr[14]=n3.z; fr[15]=n3.w;
            }
        }
        __syncthreads();
        {
            float4* dst = reinterpret_cast<float4*>(out + (size_t)sbase * NCOL);
            const float4* src = reinterpret_cast<const float4*>(bufp);
            for (int t2 = tid; t2 < (32 * NCOL) / 4; t2 += 256) dst[t2] = src[t2];
        }
    }
}

// ---------------------------------------------------------------------------
extern "C" void kernel_launch(void* const* d_in, const int* in_sizes, int n_in,
                              void* d_out, int out_size, void* d_ws, size_t ws_size,
                              hipStream_t stream)
{
    const float* X      = (const float*)d_in[0];
    const float* F      = (const float*)d_in[1];
    const float* QX     = (const float*)d_in[2];
    const float* omegaD = (const float*)d_in[3];
    const float* omegaF = (const float*)d_in[4];
    float* out = (float*)d_out;

    const int M = in_sizes[0] / 3;       // 262144
    const int K = in_sizes[3];           // 85
    const int ntile = M / 32;            // 8192

    int nb = (int)((ws_size / sizeof(float) - PBLK) / PBLK);
    if (nb > NB1) nb = NB1;
    if (nb > ntile) nb = ntile;
    if (nb < 1) nb = 1;

    float* partial = (float*)d_ws;
    float* QFbuf   = partial + (size_t)nb * PBLK;

    hipLaunchKernelGGL(k1_partial, dim3(nb), dim3(384), 0, stream,
                       X, F, QX, omegaD, K, ntile, partial);
    hipLaunchKernelGGL(k1_reduce, dim3(KP), dim3(512), 0, stream,
                       partial, omegaF, nb, QFbuf);
    hipLaunchKernelGGL(k2_out, dim3(M / 256), dim3(256), 0, stream,
                       F, QFbuf, out);
}